// Round 1
// baseline (187.825 us; speedup 1.0000x reference)
//
#include <hip/hip_runtime.h>

// Problem constants (fixed by setup_inputs): B=8, C=64, NX=NY=512.
// Scalars arrive as 1-element DEVICE arrays, so hardcode on host side.
#define BATCH 8
#define CCH   64            // num_bev_features
#define NXC   512
#define NYC   512
#define SLOTS (NXC * NYC)   // 262144 slots per batch image
#define S4    (SLOTS / 4)   // 65536 float4-groups per (b,c) plane

// Pass 1: last-write-wins winner per flat slot via atomicMax on pillar index.
// max is commutative -> deterministic regardless of wave scheduling, and
// "largest i wins" == numpy fancy-index assignment semantics.
__global__ void winner_kernel(const int* __restrict__ coords,
                              int* __restrict__ winner, int n) {
    int i = blockIdx.x * blockDim.x + threadIdx.x;
    if (i >= n) return;
    int4 c4 = *reinterpret_cast<const int4*>(coords + (size_t)i * 4);
    // coords row = [b, z, y, x]; flat = b*nx*ny + (z + y*nx + x)
    int flat = c4.x * SLOTS + c4.y + c4.z * NXC + c4.w;
    atomicMax(&winner[flat], i);
}

// Pass 2: fused zero-fill + gather. One float4 store per 4 output elems:
// out[b,c,y,x] = winner[b, y*nx+x] < 0 ? 0 : feat[winner*C + c].
// Output write is fully coalesced (16B/lane); feat (51 MiB) and winner
// (8 MiB) are L3-resident so their heavy logical re-read is absorbed.
__global__ void fill_gather_kernel(const float* __restrict__ feat,
                                   const int* __restrict__ winner,
                                   float* __restrict__ out,
                                   long total4) {
    long stride = (long)gridDim.x * blockDim.x;
    for (long e = (long)blockIdx.x * blockDim.x + threadIdx.x; e < total4; e += stride) {
        int plane = (int)(e >> 16);        // e / S4   (S4 = 65536)
        int p4    = (int)(e & (S4 - 1));   // float4-group within plane
        int b     = plane >> 6;            // plane / C (C = 64)
        int c     = plane & (CCH - 1);     // plane % C
        int4 w4 = *reinterpret_cast<const int4*>(winner + (size_t)b * SLOTS + (size_t)p4 * 4);
        float4 v;
        v.x = (w4.x < 0) ? 0.0f : feat[(size_t)w4.x * CCH + c];
        v.y = (w4.y < 0) ? 0.0f : feat[(size_t)w4.y * CCH + c];
        v.z = (w4.z < 0) ? 0.0f : feat[(size_t)w4.z * CCH + c];
        v.w = (w4.w < 0) ? 0.0f : feat[(size_t)w4.w * CCH + c];
        *reinterpret_cast<float4*>(out + e * 4) = v;
    }
}

extern "C" void kernel_launch(void* const* d_in, const int* in_sizes, int n_in,
                              void* d_out, int out_size, void* d_ws, size_t ws_size,
                              hipStream_t stream) {
    const float* feat   = (const float*)d_in[0];   // (N, 64) f32
    const int*   coords = (const int*)d_in[1];     // (N, 4)  i32
    float*       out    = (float*)d_out;           // (8, 64, 512, 512) f32
    int n = in_sizes[1] / 4;                       // N = 200000

    int* winner = (int*)d_ws;                      // 8 MiB: BATCH*SLOTS ints
    // init winner to -1 (0xFF bytes) — re-done every call, so no cross-call state
    hipMemsetAsync(winner, 0xFF, (size_t)BATCH * SLOTS * sizeof(int), stream);

    winner_kernel<<<(n + 255) / 256, 256, 0, stream>>>(coords, winner, n);

    long total4 = (long)BATCH * CCH * S4;          // 33,554,432 float4 groups
    fill_gather_kernel<<<2048, 256, 0, stream>>>(feat, winner, out, total4);
}

// Round 2
// 111.029 us; speedup vs baseline: 1.6917x; 1.6917x over previous
//
#include <hip/hip_runtime.h>

// Problem constants (fixed by setup_inputs): B=8, C=64, NX=NY=512.
#define BATCH 8
#define CCH   64            // num_bev_features
#define NXC   512
#define NYC   512
#define SLOTS (NXC * NYC)   // 262144 slots per batch image
#define S4    (SLOTS / 4)   // 65536 float4-groups per (b,c) plane

typedef float f32x4 __attribute__((ext_vector_type(4)));

// Pass 0: init winner to -1 with a properly-sized grid (runtime's
// fillBufferAligned for this buffer ran at 26 GB/s / 320us — replace it).
__global__ void init_winner(int4* __restrict__ winner4) {
    int i = blockIdx.x * blockDim.x + threadIdx.x;   // exactly BATCH*SLOTS/4 threads
    winner4[i] = make_int4(-1, -1, -1, -1);
}

// Pass 1: last-write-wins winner per flat slot via atomicMax on pillar index.
// max is commutative -> deterministic, and "largest i wins" == numpy
// fancy-index assignment semantics (matches ref; absmax was 0.0).
__global__ void winner_kernel(const int* __restrict__ coords,
                              int* __restrict__ winner, int n) {
    int i = blockIdx.x * blockDim.x + threadIdx.x;
    if (i >= n) return;
    int4 c4 = *reinterpret_cast<const int4*>(coords + (size_t)i * 4);
    int flat = c4.x * SLOTS + c4.y + c4.z * NXC + c4.w;  // b*nx*ny + z + y*nx + x
    atomicMax(&winner[flat], i);
}

// Pass 2: fused zero-fill + gather with channel-blocking.
// Thread = (batch b, channel-group cg of 8, slot-group p4 of 4 slots):
//   - 1x int4 winner read (coalesced, 8x fewer logical winner reads than 1ch/thread)
//   - per non-empty winner: 2x float4 feat reads (32B contiguous chunk of the row)
//   - 8x float4 nontemporal plane writes (coalesced; nt keeps L2 for winner/feat)
// Empty winners (w<0) skip feat loads and emit zeros.
__global__ void fill_gather2(const float* __restrict__ feat,
                             const int* __restrict__ winner,
                             float* __restrict__ out) {
    int e = blockIdx.x * blockDim.x + threadIdx.x;  // BATCH * (CCH/8) * S4 threads
    int p4 = e & (S4 - 1);          // slot-group within plane
    int cg = (e >> 16) & 7;         // channel-group (8 channels)
    int b  = e >> 19;               // batch
    const int c0 = cg * 8;

    int4 w4 = *reinterpret_cast<const int4*>(winner + (size_t)b * SLOTS + (size_t)p4 * 4);
    int w[4] = {w4.x, w4.y, w4.z, w4.w};

    float f[4][8];
    #pragma unroll
    for (int j = 0; j < 4; ++j) {
        if (w[j] >= 0) {
            const float* row = feat + (size_t)w[j] * CCH + c0;
            float4 lo = *reinterpret_cast<const float4*>(row);
            float4 hi = *reinterpret_cast<const float4*>(row + 4);
            f[j][0] = lo.x; f[j][1] = lo.y; f[j][2] = lo.z; f[j][3] = lo.w;
            f[j][4] = hi.x; f[j][5] = hi.y; f[j][6] = hi.z; f[j][7] = hi.w;
        } else {
            #pragma unroll
            for (int c = 0; c < 8; ++c) f[j][c] = 0.0f;
        }
    }

    size_t base = ((size_t)b * CCH + c0) * SLOTS + (size_t)p4 * 4;
    #pragma unroll
    for (int c = 0; c < 8; ++c) {
        f32x4 v = {f[0][c], f[1][c], f[2][c], f[3][c]};
        __builtin_nontemporal_store(v, reinterpret_cast<f32x4*>(out + base + (size_t)c * SLOTS));
    }
}

extern "C" void kernel_launch(void* const* d_in, const int* in_sizes, int n_in,
                              void* d_out, int out_size, void* d_ws, size_t ws_size,
                              hipStream_t stream) {
    const float* feat   = (const float*)d_in[0];   // (N, 64) f32
    const int*   coords = (const int*)d_in[1];     // (N, 4)  i32
    float*       out    = (float*)d_out;           // (8, 64, 512, 512) f32
    int n = in_sizes[1] / 4;                       // N = 200000

    int* winner = (int*)d_ws;                      // 8 MiB: BATCH*SLOTS ints

    // init winner = -1: BATCH*SLOTS/4 int4 stores
    init_winner<<<(BATCH * SLOTS / 4) / 256, 256, 0, stream>>>((int4*)winner);

    winner_kernel<<<(n + 255) / 256, 256, 0, stream>>>(coords, winner, n);

    int total_threads = BATCH * (CCH / 8) * S4;    // 4,194,304
    fill_gather2<<<total_threads / 256, 256, 0, stream>>>(feat, winner, out);
}